// Round 4
// baseline (568.461 us; speedup 1.0000x reference)
//
#include <hip/hip_runtime.h>

#define N_COLS 4096
#define BLOCK 256
#define ROWS_PER_BLOCK 4   // one row per wave, 4 waves per block, no barriers
#define EPS 1e-7f

// clang-native vector type for nontemporal builtins (HIP's float4 is a class)
typedef float floatx4 __attribute__((ext_vector_type(4)));

// compare-exchange keeping the LARGER value in `a` (descending order)
__device__ __forceinline__ void cswap_desc(float& a, float& b) {
    float hi = fmaxf(a, b);
    b = fminf(a, b);
    a = hi;
}

// Batcher odd-even mergesort for 8 elements, 19 comparators, descending.
__device__ __forceinline__ void sort8_desc(float v[8]) {
    cswap_desc(v[0], v[1]); cswap_desc(v[2], v[3]); cswap_desc(v[4], v[5]); cswap_desc(v[6], v[7]);
    cswap_desc(v[0], v[2]); cswap_desc(v[1], v[3]); cswap_desc(v[4], v[6]); cswap_desc(v[5], v[7]);
    cswap_desc(v[1], v[2]); cswap_desc(v[5], v[6]);
    cswap_desc(v[0], v[4]); cswap_desc(v[1], v[5]); cswap_desc(v[2], v[6]); cswap_desc(v[3], v[7]);
    cswap_desc(v[2], v[4]); cswap_desc(v[3], v[5]);
    cswap_desc(v[1], v[2]); cswap_desc(v[3], v[4]); cswap_desc(v[5], v[6]);
}

// Merge sorted-desc b[8] into sorted-desc a[8], keeping the top-8 (sorted desc).
// Bitonic split (max(a[i], b[7-i])) + 3-stage bitonic clean (12 comparators).
__device__ __forceinline__ void merge8(float a[8], const float b[8]) {
    float t[8];
#pragma unroll
    for (int i = 0; i < 8; ++i) t[i] = fmaxf(a[i], b[7 - i]);
    cswap_desc(t[0], t[4]); cswap_desc(t[1], t[5]); cswap_desc(t[2], t[6]); cswap_desc(t[3], t[7]);
    cswap_desc(t[0], t[2]); cswap_desc(t[1], t[3]); cswap_desc(t[4], t[6]); cswap_desc(t[5], t[7]);
    cswap_desc(t[0], t[1]); cswap_desc(t[2], t[3]); cswap_desc(t[4], t[5]); cswap_desc(t[6], t[7]);
#pragma unroll
    for (int i = 0; i < 8; ++i) a[i] = t[i];
}

__global__ __launch_bounds__(BLOCK, 8) void sparse_attn_topk_kernel(
    const float* __restrict__ in, float* __restrict__ out, int n_rows) {
    const int lane = threadIdx.x & 63;
    const int wave = threadIdx.x >> 6;        // 0..3
    const int row  = blockIdx.x * ROWS_PER_BLOCK + wave;
    if (row >= n_rows) return;                // wave-uniform

    const size_t base = (size_t)row * N_COLS;
    const float4* in4 = reinterpret_cast<const float4*>(in + base);   // 1024 f4/row
    floatx4* out4     = reinterpret_cast<floatx4*>(out + base);

    // ---- pass 1: per-lane top-8 over 64 elements (8 batches of 8) ----
    float a[8], b[8];
    {
        float4 v0 = in4[lane];
        float4 v1 = in4[lane + 64];
        a[0] = v0.x; a[1] = v0.y; a[2] = v0.z; a[3] = v0.w;
        a[4] = v1.x; a[5] = v1.y; a[6] = v1.z; a[7] = v1.w;
        sort8_desc(a);
    }
#pragma unroll
    for (int j = 1; j < 8; ++j) {
        float4 v0 = in4[j * 128 + lane];
        float4 v1 = in4[j * 128 + 64 + lane];
        b[0] = v0.x; b[1] = v0.y; b[2] = v0.z; b[3] = v0.w;
        b[4] = v1.x; b[5] = v1.y; b[6] = v1.z; b[7] = v1.w;
        sort8_desc(b);
        merge8(a, b);
    }

    // ---- wave butterfly: all 64 lanes converge to the row's top-8 ----
#pragma unroll
    for (int d = 1; d < 64; d <<= 1) {
#pragma unroll
        for (int i = 0; i < 8; ++i) b[i] = __shfl_xor(a[i], d, 64);
        merge8(a, b);
    }

    const float delta = a[7] + EPS;  // 8th largest + eps

    // Every row element > topv[7] is contained in the top-8 multiset, and
    // elements == topv[7] clip to exactly 0 — so the full-row clipped sum
    // equals the clipped sum over the merged top-8. No second reduction,
    // no cross-wave communication needed at all.
    float total = 0.0f;
#pragma unroll
    for (int i = 0; i < 8; ++i) total += fmaxf(a[i] - delta, 0.0f);
    const float inv = 1.0f / (total + EPS);

    // ---- pass 2: re-read row (L2/L3-hot) and stream out nontemporally ----
#pragma unroll
    for (int k = 0; k < 16; ++k) {
        float4 v = in4[k * 64 + lane];
        floatx4 o;
        o.x = fmaxf(v.x - delta, 0.0f) * inv;
        o.y = fmaxf(v.y - delta, 0.0f) * inv;
        o.z = fmaxf(v.z - delta, 0.0f) * inv;
        o.w = fmaxf(v.w - delta, 0.0f) * inv;
        __builtin_nontemporal_store(o, &out4[k * 64 + lane]);
    }
}

extern "C" void kernel_launch(void* const* d_in, const int* in_sizes, int n_in,
                              void* d_out, int out_size, void* d_ws, size_t ws_size,
                              hipStream_t stream) {
    const float* attn_s = (const float*)d_in[0];
    float* out = (float*)d_out;
    const int n_rows = in_sizes[0] / N_COLS;  // 16384
    const int grid = (n_rows + ROWS_PER_BLOCK - 1) / ROWS_PER_BLOCK;
    sparse_attn_topk_kernel<<<grid, BLOCK, 0, stream>>>(attn_s, out, n_rows);
}